// Round 11
// baseline (7668.002 us; speedup 1.0000x reference)
//
#include <hip/hip_runtime.h>
#include <stdint.h>

// Farthest point sampling: b=16, n=65536, npoints=2048. Full-f64 decision
// pipeline (R5: harness ref is float64 ground-truth recompute).
//
// R27 = R23 (4.26 ms proven) + LDS-destination pipelined polling + coord-
// carrying 32B quarters.
// R25/R26 post-mortem: pipelined REGISTER polls are unfixable at HIP level
// (in-flight loads land into reallocated VGPRs; backend waitcnt pass is
// blind to asm loads -> corrupted live registers, absmax 1e8-1e9). R27
// keeps the pipeline but lands polls in LDS SCRATCH via
// __builtin_amdgcn_global_load_lds (vmcnt decrement == LDS write done):
//  - pbuf[4][2][64][2] (8KB): 4 rotating rounds x 32B/lane (two 16B
//    half-loads). Stale in-flight ops write scratch; tags gate; worst case
//    one extra round. NO register hazards by construction.
//  - staggered prologue (s_sleep(4) between round issues) -> steady-state
//    samples every ~256cy instead of every ~900cy (the serial-poll
//    quantization that R21/R22/R23 left as the only surviving theory).
//  - vmcnt(6) confirms the checked round landed (4 rounds x 2 ops ring).
//  - coord-carrying quarters (w0=bd_hi|tag|bi w1=bd_lo|tag|bi
//    w2=x|tag|y_hi w3=z|tag|y_lo): post-detect tail is VMEM-free (ballot +
//    readlane only) -> no compiler-inserted vmcnt drain in the tail.
//  - publisher carries candidate f32 coords through the update loop
//    (cndmask, literal j) + 3 readlanes from the winning lane.
// aux=16 (SC1, device scope) on the LDS loads -- same visibility class as
// the proven escalation spin. If SC1 encoding is wrong the polls go stale
// and the escalation rescues correctness (slow-not-wrong, R21 signature).
// Narrow fallback (ws_size < 64KB): R23 protocol verbatim.
// Everything else R23 verbatim: DPP/permlane butterflies, pre-widened f64,
// per-wave publish via atomic_swap_x2, own-quarter register substitution,
// LDS coord mailbox for waves1-3, parity double-buffer, unique 16-bit tags
// (poison 0 unmatchable), skew<=1, guards never hang.

#define NBATCH   16
#define NPTS     65536
#define NPOINTS  2048
#define KBLK     16                  // blocks per batch
#define THREADS  256
#define PPB      4096                // points per block
#define PPT      16                  // points per thread
#define QPB      4                   // quarters (waves) per block
// narrow (R23) layout: 16B quarters
#define SLOT_N   2
#define REGION_N (KBLK * QPB * SLOT_N)   // 128 u64 = 1 KB per (parity,batch)
// wide layout: 32B quarters
#define SLOT_W   4
#define REGION_W (KBLK * QPB * SLOT_W)   // 256 u64 = 2 KB per (parity,batch)
#define WS_NEED_WIDE (2 * NBATCH * REGION_W * 8)  // 65536 B

#define TAGOK(w) (((unsigned)((w) >> 16) & 0xFFFFu) == tag)

typedef unsigned int uint4v __attribute__((ext_vector_type(4)));
typedef unsigned int uint2v __attribute__((ext_vector_type(2)));
typedef unsigned long long ull;

// One 16-B device-scope load covering both narrow quarter words.
__device__ __forceinline__ void load_slot16(const ull* p, ull& w0, ull& w1) {
    uint4v r;
    asm volatile("global_load_dwordx4 %0, %1, off sc1\n\t"
                 "s_waitcnt vmcnt(0)"
                 : "=v"(r) : "v"(p) : "memory");
    w0 = ((ull)r.y << 32) | r.x;
    w1 = ((ull)r.w << 32) | r.z;
}

// ---- argmax butterfly stages: (d,i) <- winner of self and partner ----
__device__ __forceinline__ void red_combine(double& d, int& i,
                                            double od, int oi) {
    const bool t = (od > d) || (od == d && oi < i);
    d = t ? od : d; i = t ? oi : i;
}

template <int CTRL>
__device__ __forceinline__ void red_dpp(double& d, int& i) {
    const int hi = __double2hiint(d), lo = __double2loint(d);
    const int ohi = __builtin_amdgcn_update_dpp(hi, hi, CTRL, 0xF, 0xF, false);
    const int olo = __builtin_amdgcn_update_dpp(lo, lo, CTRL, 0xF, 0xF, false);
    const int oi  = __builtin_amdgcn_update_dpp(i,  i,  CTRL, 0xF, 0xF, false);
    red_combine(d, i, __hiloint2double(ohi, olo), oi);
}

__device__ __forceinline__ void red_swz16(double& d, int& i) {
    const int ohi = __builtin_amdgcn_ds_swizzle(__double2hiint(d), 0x401F);
    const int olo = __builtin_amdgcn_ds_swizzle(__double2loint(d), 0x401F);
    const int oi  = __builtin_amdgcn_ds_swizzle(i, 0x401F);
    red_combine(d, i, __hiloint2double(ohi, olo), oi);
}

__device__ __forceinline__ void red_x32(double& d, int& i, bool hi_half) {
    const unsigned hi = (unsigned)__double2hiint(d);
    const unsigned lo = (unsigned)__double2loint(d);
    uint2v rh = __builtin_amdgcn_permlane32_swap(hi, hi, false, false);
    uint2v rl = __builtin_amdgcn_permlane32_swap(lo, lo, false, false);
    uint2v ri = __builtin_amdgcn_permlane32_swap((unsigned)i, (unsigned)i,
                                                 false, false);
    const int ohi = (int)(hi_half ? rh[0] : rh[1]);
    const int olo = (int)(hi_half ? rl[0] : rl[1]);
    const int oi  = (int)(hi_half ? ri[0] : ri[1]);
    red_combine(d, i, __hiloint2double(ohi, olo), oi);
}

__device__ __forceinline__ void argmax64(double& d, int& i, bool hi_half) {
    red_dpp<0xB1>(d, i);    // xor1
    red_dpp<0x4E>(d, i);    // xor2
    red_dpp<0x141>(d, i);   // i^7 -> 8-max
    red_dpp<0x140>(d, i);   // i^15 -> 16-max
    red_swz16(d, i);        // xor16 -> 32-max
    red_x32(d, i, hi_half); // xor32 -> 64-max
}

template <int WIDE>
__global__ __launch_bounds__(THREADS, 1)
void fps_kernel(const float* __restrict__ pts, int* __restrict__ out,
                ull* __restrict__ slots)
{
    const int bid  = blockIdx.x;
    const int g    = bid & 15;       // batch (XCD co-location swizzle)
    const int blk  = bid >> 4;       // block within batch, 0..15
    const int tid  = threadIdx.x;
    const int lane = tid & 63;
    const int wave = tid >> 6;       // 0..3
    const bool hi_half = (lane >= 32);

    const float* __restrict__ P = pts + (size_t)g * (NPTS * 3);

    __shared__ ull s_mail[2][4];     // [par][k] = coord_k|tag, k=0..2
    // LDS poll scratch: [round][half][lane][word]; in-flight loads land
    // here, never in registers. Uninitialized is fine: a round is only
    // CHECKED after vmcnt confirms its load landed.
    __shared__ ull pbuf[4][2][64][2];

    // Pre-widened f64 coords + f32 shadows (wide path coord carry) + dist.
    double xd[PPT], yd[PPT], zd[PPT], dist[PPT];
    float  xf[PPT], yf[PPT], zf[PPT];
    const int base = blk * PPB;
#pragma unroll
    for (int j = 0; j < PPT; ++j) {
        const int idx = base + j * THREADS + tid;
        const float a = P[idx * 3 + 0];
        const float b = P[idx * 3 + 1];
        const float c = P[idx * 3 + 2];
        xd[j] = (double)a; yd[j] = (double)b; zd[j] = (double)c;
        if (WIDE) { xf[j] = a; yf[j] = b; zf[j] = c; }
        dist[j] = 1e10;
    }
    if (tid < 8) ((ull*)s_mail)[tid] = 0ull;  // tags never 0
    __syncthreads();

    double qx = (double)P[0], qy = (double)P[1], qz = (double)P[2];
    if (blk == 0 && tid == 0) out[g * NPOINTS] = 0;

    for (int it = 0; it < NPOINTS - 1; ++it) {
        // ---- f64 min-dist update + thread-local argmax (first-max) ----
        double bd = -1.0;
        int    bi = 0x7FFFFFFF;
        float  bx = 0.f, by = 0.f, bz = 0.f;   // wide: candidate coords
        {
#pragma clang fp contract(off)
#pragma unroll
            for (int j = 0; j < PPT; ++j) {
                const double dx = xd[j] - qx;
                const double dy = yd[j] - qy;
                const double dz = zd[j] - qz;
                const double d  = (dx * dx + dy * dy) + dz * dz;
                const double nd = fmin(dist[j], d);
                dist[j] = nd;
                const bool t = nd > bd;
                bd = t ? nd : bd;
                bi = t ? (base + j * THREADS + tid) : bi;
                if (WIDE) {
                    bx = t ? xf[j] : bx;   // j literal: no runtime indexing
                    by = t ? yf[j] : by;
                    bz = t ? zf[j] : bz;
                }
            }
        }

        // ---- 64-lane argmax butterfly (DPP/permlane transport) ----
        argmax64(bd, bi, hi_half);

        const unsigned tag = (unsigned)(it + 1);
        const int par = it & 1;
        ull* rb = slots + (size_t)(par * NBATCH + g)
                        * (WIDE ? REGION_W : REGION_N);

        // ---- this wave's quarter words ----
        const ull B  = (ull)__double_as_longlong(bd);
        const ull TI = ((ull)tag << 16) | (ull)((unsigned)bi & 0xFFFFu);
        const ull own0 = ((B >> 32) << 32) | TI;
        const ull own1 = ((B & 0xFFFFFFFFull) << 32) | TI;
        ull own2 = 0, own3 = 0;
        if (WIDE) {
            // winner coords from the source lane: (bi-base)&63 == winner's
            // lane within this wave (stride 256 == 0 mod 64); that lane's
            // thread-local candidate IS the wave winner.
            const int src_lane = (bi - base) & 63;
            const unsigned xw = (unsigned)__builtin_amdgcn_readlane(
                                    __float_as_int(bx), src_lane);
            const unsigned yw = (unsigned)__builtin_amdgcn_readlane(
                                    __float_as_int(by), src_lane);
            const unsigned zw = (unsigned)__builtin_amdgcn_readlane(
                                    __float_as_int(bz), src_lane);
            own2 = ((ull)xw << 32) | ((ull)tag << 16) | (ull)(yw >> 16);
            own3 = ((ull)zw << 32) | ((ull)tag << 16) | (ull)(yw & 0xFFFFu);
        }

        // ---- per-wave publish via no-return atomic swap ----
        if (WIDE) {
            if (lane < 4) {
                ull* dst = rb + (blk * QPB + wave) * SLOT_W + lane;
                const ull v = (lane == 0) ? own0 : (lane == 1) ? own1
                            : (lane == 2) ? own2 : own3;
                asm volatile("global_atomic_swap_x2 %0, %1, off"
                             :: "v"(dst), "v"(v) : "memory");
            }
        } else {
            if (lane < 2) {
                ull* dst = rb + (blk * QPB + wave) * SLOT_N + lane;
                const ull v = (lane == 0) ? own0 : own1;
                asm volatile("global_atomic_swap_x2 %0, %1, off"
                             :: "v"(dst), "v"(v) : "memory");
            }
        }

        float qxf, qyf, qzf;

        if (wave != 0) {
            // ---- winner coords from LDS (3 self-tagged words) ----
            ull f1, f2, f3;
            int guard = 0;
            bool okm;
            do {
                f1 = __hip_atomic_load(&s_mail[par][0], __ATOMIC_RELAXED,
                                       __HIP_MEMORY_SCOPE_WORKGROUP);
                f2 = __hip_atomic_load(&s_mail[par][1], __ATOMIC_RELAXED,
                                       __HIP_MEMORY_SCOPE_WORKGROUP);
                f3 = __hip_atomic_load(&s_mail[par][2], __ATOMIC_RELAXED,
                                       __HIP_MEMORY_SCOPE_WORKGROUP);
                okm = ((unsigned)f1 == tag) & ((unsigned)f2 == tag)
                    & ((unsigned)f3 == tag);
            } while (!okm && ++guard < (1 << 20));
            qxf = __int_as_float((int)(f1 >> 32));
            qyf = __int_as_float((int)(f2 >> 32));
            qzf = __int_as_float((int)(f3 >> 32));
        } else if (WIDE) {
            // ======== wide wave0: LDS-destination pipelined poll ========
            ull* sp = rb + lane * SLOT_W;    // this lane's 32B quarter
            const bool own = (lane == blk * QPB);
            ull l0 = own0, l1 = own1, l2 = own2, l3 = own3;
            bool ok = own;

// 16B per lane into LDS at base+lane*16; aux=16 = SC1 (device scope).
#define GLDS(gp, lp)                                                  \
    __builtin_amdgcn_global_load_lds(                                 \
        (const __attribute__((address_space(1))) void*)(gp),          \
        (__attribute__((address_space(3))) void*)(lp), 16, 0, 16)

            // staggered prologue: rounds end up sampling the line every
            // ~256cy in steady state instead of every ~900cy (serial).
            __builtin_amdgcn_s_sleep(2);
            GLDS(sp,     &pbuf[0][0][0][0]);
            GLDS(sp + 2, &pbuf[0][1][0][0]);
            __builtin_amdgcn_s_sleep(4);
            GLDS(sp,     &pbuf[1][0][0][0]);
            GLDS(sp + 2, &pbuf[1][1][0][0]);
            __builtin_amdgcn_s_sleep(4);
            GLDS(sp,     &pbuf[2][0][0][0]);
            GLDS(sp + 2, &pbuf[2][1][0][0]);
            __builtin_amdgcn_s_sleep(4);
            GLDS(sp,     &pbuf[3][0][0][0]);
            GLDS(sp + 2, &pbuf[3][1][0][0]);

#define CHECKL(r)                                                     \
    {                                                                 \
        const ull t0 = pbuf[r][0][lane][0];                           \
        const ull t1 = pbuf[r][0][lane][1];                           \
        const ull t2 = pbuf[r][1][lane][0];                           \
        const ull t3 = pbuf[r][1][lane][1];                           \
        const bool hit = (!ok) & TAGOK(t0) & TAGOK(t1)                \
                               & TAGOK(t2) & TAGOK(t3);               \
        l0 = hit ? t0 : l0; l1 = hit ? t1 : l1;                       \
        l2 = hit ? t2 : l2; l3 = hit ? t3 : l3;                       \
        ok |= hit;                                                    \
    }
// vmcnt(6): exactly 6 loads (rounds r+1..r+3) are younger than round r's
// pair -> waiting to 6 outstanding proves round r landed in LDS.
#define PH(r)                                                         \
    asm volatile("s_waitcnt vmcnt(6)" ::: "memory");                  \
    __builtin_amdgcn_sched_barrier(0);                                \
    CHECKL(r);                                                        \
    allok = __all(ok);                                                \
    if (allok) break;                                                 \
    GLDS(sp,     &pbuf[r][0][0][0]);                                  \
    GLDS(sp + 2, &pbuf[r][1][0][0]);

            int rounds = 0;
            bool allok = __all(ok);
            while (!allok && rounds < 64) {
                PH(0);
                PH(1);
                PH(2);
                PH(3);
                rounds += 4;
            }
            if (!allok) {
                // escalation: proven agent atomic spin; its compiler-
                // inserted vmcnt drain lands stale ops into LDS scratch.
                int g2 = 0;
                while (!ok) {
                    l0 = __hip_atomic_load(sp + 0, __ATOMIC_RELAXED,
                                           __HIP_MEMORY_SCOPE_AGENT);
                    l1 = __hip_atomic_load(sp + 1, __ATOMIC_RELAXED,
                                           __HIP_MEMORY_SCOPE_AGENT);
                    l2 = __hip_atomic_load(sp + 2, __ATOMIC_RELAXED,
                                           __HIP_MEMORY_SCOPE_AGENT);
                    l3 = __hip_atomic_load(sp + 3, __ATOMIC_RELAXED,
                                           __HIP_MEMORY_SCOPE_AGENT);
                    ok = TAGOK(l0) & TAGOK(l1) & TAGOK(l2) & TAGOK(l3);
                    if (++g2 > (1 << 20)) break;
                }
            }

            double cd = __longlong_as_double(
                (long long)(((l0 >> 32) << 32) | (l1 >> 32)));
            int    ci = (int)(l0 & 0xFFFFull);
            const int si = ci;
            // decode this lane's candidate coords (registers, no memory)
            const unsigned xb = (unsigned)(l2 >> 32);
            const unsigned zb = (unsigned)(l3 >> 32);
            const unsigned yb = (((unsigned)l2 & 0xFFFFu) << 16)
                              |  ((unsigned)l3 & 0xFFFFu);

            argmax64(cd, ci, hi_half);

            if (lane == 0 && blk == 0) out[g * NPOINTS + it + 1] = ci;

            // winning lane -> broadcast its carried coords (quarter
            // candidate indices are unique: disjoint tid partitions).
            const ull mb = __ballot(si == ci);
            const int wl = (__ffsll(mb) - 1) & 63;
            qxf = __int_as_float(__builtin_amdgcn_readlane((int)xb, wl));
            qyf = __int_as_float(__builtin_amdgcn_readlane((int)yb, wl));
            qzf = __int_as_float(__builtin_amdgcn_readlane((int)zb, wl));

            if (lane < 3) {
                const unsigned coord =
                    (lane == 0) ? (unsigned)__float_as_int(qxf)
                  : (lane == 1) ? (unsigned)__float_as_int(qyf)
                                : (unsigned)__float_as_int(qzf);
                __hip_atomic_store(&s_mail[par][lane],
                                   ((ull)coord << 32) | (ull)tag,
                                   __ATOMIC_RELAXED,
                                   __HIP_MEMORY_SCOPE_WORKGROUP);
            }
        } else {
            // ======== narrow wave0: R23 serial poll (verbatim) ========
            ull* sp = rb + lane * SLOT_N;
            const bool own = (lane == blk * QPB);
            ull l0 = own0, l1 = own1;
            bool ok = own;
            __builtin_amdgcn_s_sleep(12);
            int g1 = 0;
            while (!ok && g1 < 32) {
                load_slot16(sp, l0, l1);
                ok = TAGOK(l0) & TAGOK(l1);
                ++g1;
            }
            int g2 = 0;
            while (!ok) {
                l0 = __hip_atomic_load(sp + 0, __ATOMIC_RELAXED,
                                       __HIP_MEMORY_SCOPE_AGENT);
                l1 = __hip_atomic_load(sp + 1, __ATOMIC_RELAXED,
                                       __HIP_MEMORY_SCOPE_AGENT);
                ok = TAGOK(l0) & TAGOK(l1);
                if (++g2 > (1 << 20)) break;
            }

            double cd = __longlong_as_double(
                (long long)(((l0 >> 32) << 32) | (l1 >> 32)));
            int    ci = (int)(l0 & 0xFFFFull);

            const int    si = ci;
            const float* pc = P + (size_t)(unsigned)si * 3;
            const float px = pc[0];
            const float py = pc[1];
            const float pz = pc[2];

            argmax64(cd, ci, hi_half);

            if (lane == 0 && blk == 0) out[g * NPOINTS + it + 1] = ci;

            const ull mb = __ballot(si == ci);
            const int wl = (__ffsll(mb) - 1) & 63;
            qxf = __int_as_float(
                __builtin_amdgcn_readlane(__float_as_int(px), wl));
            qyf = __int_as_float(
                __builtin_amdgcn_readlane(__float_as_int(py), wl));
            qzf = __int_as_float(
                __builtin_amdgcn_readlane(__float_as_int(pz), wl));

            if (lane < 3) {
                const unsigned coord =
                    (lane == 0) ? (unsigned)__float_as_int(qxf)
                  : (lane == 1) ? (unsigned)__float_as_int(qyf)
                                : (unsigned)__float_as_int(qzf);
                __hip_atomic_store(&s_mail[par][lane],
                                   ((ull)coord << 32) | (ull)tag,
                                   __ATOMIC_RELAXED,
                                   __HIP_MEMORY_SCOPE_WORKGROUP);
            }
        }

        qx = (double)qxf; qy = (double)qyf; qz = (double)qzf;
    }
}

extern "C" void kernel_launch(void* const* d_in, const int* in_sizes, int n_in,
                              void* d_out, int out_size, void* d_ws, size_t ws_size,
                              hipStream_t stream) {
    (void)in_sizes; (void)n_in; (void)out_size;
    const float* t_in = (const float*)d_in[1];
    int* out = (int*)d_out;
    ull* slots = (ull*)d_ws;

    dim3 grid(NBATCH * KBLK);
    dim3 block(THREADS);
    void* args[] = { (void*)&t_in, (void*)&out, (void*)&slots };
    const void* kfn = (ws_size >= (size_t)WS_NEED_WIDE)
        ? (const void*)fps_kernel<1>
        : (const void*)fps_kernel<0>;
    hipLaunchCooperativeKernel(kfn, grid, block, args, 0, stream);
}

// Round 13
// 4677.324 us; speedup vs baseline: 1.6394x; 1.6394x over previous
//
#include <hip/hip_runtime.h>
#include <stdint.h>

// Farthest point sampling: b=16, n=65536, npoints=2048. Full-f64 decision
// pipeline (R5: harness ref is float64 ground-truth recompute).
//
// R29 = R28 (TDMA polling over the proven R23 protocol) with BOUNDED
// pacing guards -- R28's bench died at the container level, and its
// epoch-spin worst case (1<<20 clock reads x 64 rounds) could wedge the
// box if the realtime tick-rate assumption is off. R29 caps the blast
// radius: inner spin <= 512 clock reads, aligned rounds <= 8, then
// reverts to the PROVEN free-running serial poll (R23, 32 rounds), then
// the proven agent-atomic escalation. Worst case ~0.2ms/iter bounded;
// realistic path 1-3 aligned rounds.
//
// Theory (R27 closed "poll more often": pipelined polls' traffic DELAYED
// the publishes, FETCH 7x, +80% -- R12's law): the ~2000cy gap over the
// minimum chain is STRAGGLER SKEW + GRID MISALIGNMENT -- each block's
// detect snaps to its own free-running poll grid (phase ~U(0,L~900cy));
// slowest of 16 gates the batch; skew re-seeds every iteration. Fix:
// align all polls to a GLOBAL clock grid (s_memrealtime, fixed-frequency,
// uniform across XCDs). Wave0 spins SALU-only to the next absolute epoch
// (32 ticks ~ 768cy @100MHz), then issues ONE 16-line gather. Detects
// align -> publishes align -> caught together next epoch. Poll traffic
// DROPS vs free-running (alignment signature: FETCH below R23's ~23MB).
//
// Protocol (R23, proven 4.26ms, absmax 0): 16 blocks x 256 thr per batch;
// pre-widened f64 coords; DPP/permlane argmax butterflies; per-wave
// publish of 16B quarters via atomic_swap_x2 (single writer per word);
// wave0 polls 64 quarters (lane i watches quarter i, own-quarter register
// substitution); speculative P[] coord prefetch + ballot(si==ci) +
// readlane broadcast; waves1-3 spin on 3 self-tagged LDS coord words;
// parity double-buffer; unique 16-bit tags (poison 0 unmatchable);
// skew<=1; all spins guarded -- fail slow, never hang, never wrong.
// Tripwires: WRITE_SIZE exactly 65632 KB; FETCH_SIZE drop = alignment.

#define NBATCH   16
#define NPTS     65536
#define NPOINTS  2048
#define KBLK     16                  // blocks per batch
#define THREADS  256
#define PPB      4096                // points per block
#define PPT      16                  // points per thread
#define QPB      4                   // quarters (waves) per block
#define SLOT_U64 2                   // 16 B per wave-quarter
#define REGION_U64 (KBLK * QPB * SLOT_U64) // 128 u64 = 1 KB per (parity,batch)

#define TAGOK(w) (((unsigned)((w) >> 16) & 0xFFFFu) == tag)

// TDMA epoch: 32 realtime ticks (~320ns @100MHz ~ 768 core cy @2.4GHz)
#define EPOCH_SHIFT 5
#define SPIN_CAP    512              // max clock reads per epoch wait
#define ALIGNED_MAX 8                // aligned rounds before fallback

typedef unsigned int uint4v __attribute__((ext_vector_type(4)));
typedef unsigned int uint2v __attribute__((ext_vector_type(2)));
typedef unsigned long long ull;

// One 16-B device-scope load covering both quarter words.
__device__ __forceinline__ void load_slot16(const ull* p, ull& w0, ull& w1) {
    uint4v r;
    asm volatile("global_load_dwordx4 %0, %1, off sc1\n\t"
                 "s_waitcnt vmcnt(0)"
                 : "=v"(r) : "v"(p) : "memory");
    w0 = ((ull)r.y << 32) | r.x;
    w1 = ((ull)r.w << 32) | r.z;
}

// ---- argmax butterfly stages: (d,i) <- winner of self and partner ----
__device__ __forceinline__ void red_combine(double& d, int& i,
                                            double od, int oi) {
    const bool t = (od > d) || (od == d && oi < i);
    d = t ? od : d; i = t ? oi : i;
}

template <int CTRL>
__device__ __forceinline__ void red_dpp(double& d, int& i) {
    const int hi = __double2hiint(d), lo = __double2loint(d);
    const int ohi = __builtin_amdgcn_update_dpp(hi, hi, CTRL, 0xF, 0xF, false);
    const int olo = __builtin_amdgcn_update_dpp(lo, lo, CTRL, 0xF, 0xF, false);
    const int oi  = __builtin_amdgcn_update_dpp(i,  i,  CTRL, 0xF, 0xF, false);
    red_combine(d, i, __hiloint2double(ohi, olo), oi);
}

__device__ __forceinline__ void red_swz16(double& d, int& i) {
    // ds_swizzle BitMode xor16: offset = (16<<10) | 0x1F = 0x401F
    const int ohi = __builtin_amdgcn_ds_swizzle(__double2hiint(d), 0x401F);
    const int olo = __builtin_amdgcn_ds_swizzle(__double2loint(d), 0x401F);
    const int oi  = __builtin_amdgcn_ds_swizzle(i, 0x401F);
    red_combine(d, i, __hiloint2double(ohi, olo), oi);
}

__device__ __forceinline__ void red_x32(double& d, int& i, bool hi_half) {
    // permlane32_swap(v,v): partner = hi_half ? r[0] : r[1].
    const unsigned hi = (unsigned)__double2hiint(d);
    const unsigned lo = (unsigned)__double2loint(d);
    uint2v rh = __builtin_amdgcn_permlane32_swap(hi, hi, false, false);
    uint2v rl = __builtin_amdgcn_permlane32_swap(lo, lo, false, false);
    uint2v ri = __builtin_amdgcn_permlane32_swap((unsigned)i, (unsigned)i,
                                                 false, false);
    const int ohi = (int)(hi_half ? rh[0] : rh[1]);
    const int olo = (int)(hi_half ? rl[0] : rl[1]);
    const int oi  = (int)(hi_half ? ri[0] : ri[1]);
    red_combine(d, i, __hiloint2double(ohi, olo), oi);
}

// Full 64-lane argmax (all lanes end with the global winner).
__device__ __forceinline__ void argmax64(double& d, int& i, bool hi_half) {
    red_dpp<0xB1>(d, i);    // xor1  (quad_perm 1,0,3,2)
    red_dpp<0x4E>(d, i);    // xor2  (quad_perm 2,3,0,1)
    red_dpp<0x141>(d, i);   // i^7 row_half_mirror -> 8-max
    red_dpp<0x140>(d, i);   // i^15 row_mirror     -> 16-max
    red_swz16(d, i);        // xor16               -> 32-max
    red_x32(d, i, hi_half); // xor32               -> 64-max
}

__global__ __launch_bounds__(THREADS, 1)
void fps_kernel(const float* __restrict__ pts, int* __restrict__ out,
                ull* __restrict__ slots)
{
    const int bid  = blockIdx.x;
    const int g    = bid & 15;       // batch (XCD co-location swizzle)
    const int blk  = bid >> 4;       // block within batch, 0..15
    const int tid  = threadIdx.x;
    const int lane = tid & 63;
    const int wave = tid >> 6;       // 0..3
    const bool hi_half = (lane >= 32);

    const float* __restrict__ P = pts + (size_t)g * (NPTS * 3);

    // mailbox: [par][k] = coord_k|tag for k=0,1,2 (x,y,z); [3] unused pad
    __shared__ ull s_mail[2][4];

    // Pre-widened f64 coords (cvt paid ONCE, not per iteration) + f64 dist.
    double xd[PPT], yd[PPT], zd[PPT], dist[PPT];
    const int base = blk * PPB;
#pragma unroll
    for (int j = 0; j < PPT; ++j) {
        const int idx = base + j * THREADS + tid;
        xd[j] = (double)P[idx * 3 + 0];
        yd[j] = (double)P[idx * 3 + 1];
        zd[j] = (double)P[idx * 3 + 2];
        dist[j] = 1e10;              // never survives iteration 0
    }
    if (tid < 8) ((ull*)s_mail)[tid] = 0ull;  // tags never 0
    __syncthreads();                 // once, before the loop

    double qx = (double)P[0], qy = (double)P[1], qz = (double)P[2];
    if (blk == 0 && tid == 0) out[g * NPOINTS] = 0;

    for (int it = 0; it < NPOINTS - 1; ++it) {
        // ---- f64 min-dist update + thread-local argmax (first-max) ----
        double bd = -1.0;
        int    bi = 0x7FFFFFFF;
        {
#pragma clang fp contract(off)
#pragma unroll
            for (int j = 0; j < PPT; ++j) {
                const double dx = xd[j] - qx;
                const double dy = yd[j] - qy;
                const double dz = zd[j] - qz;
                const double d  = (dx * dx + dy * dy) + dz * dz;
                const double nd = fmin(dist[j], d);
                dist[j] = nd;
                const bool t = nd > bd;          // strict: first-max kept
                bd = t ? nd : bd;
                bi = t ? (base + j * THREADS + tid) : bi;
            }
        }

        // ---- 64-lane argmax butterfly (DPP/permlane transport) ----
        argmax64(bd, bi, hi_half);

        const unsigned tag = (unsigned)(it + 1);
        const int par = it & 1;
        ull* rb = slots + (size_t)(par * NBATCH + g) * REGION_U64;

        // ---- this wave's quarter words (publish + own substitution) ----
        const ull B  = (ull)__double_as_longlong(bd);
        const ull TI = ((ull)tag << 16) | (ull)((unsigned)bi & 0xFFFFu);
        const ull own0 = ((B >> 32) << 32) | TI;
        const ull own1 = ((B & 0xFFFFFFFFull) << 32) | TI;

        // ---- per-wave publish via no-return atomic swap (single writer
        //      per word -> swap == store) ----
        if (lane < 2) {
            ull* dst = rb + (blk * QPB + wave) * SLOT_U64 + lane;
            const ull v = (lane == 0) ? own0 : own1;
            asm volatile("global_atomic_swap_x2 %0, %1, off"
                         :: "v"(dst), "v"(v) : "memory");
        }

        float qxf, qyf, qzf;         // this iteration's winner coords (f32)

        if (wave != 0) {
            // ---- winner coords from LDS (3 self-tagged words). This IS
            //      the rendezvous; parity leftovers carry tag it-1 ----
            ull f1, f2, f3;
            int guard = 0;
            bool okm;
            do {
                f1 = __hip_atomic_load(&s_mail[par][0], __ATOMIC_RELAXED,
                                       __HIP_MEMORY_SCOPE_WORKGROUP);
                f2 = __hip_atomic_load(&s_mail[par][1], __ATOMIC_RELAXED,
                                       __HIP_MEMORY_SCOPE_WORKGROUP);
                f3 = __hip_atomic_load(&s_mail[par][2], __ATOMIC_RELAXED,
                                       __HIP_MEMORY_SCOPE_WORKGROUP);
                okm = ((unsigned)f1 == tag) & ((unsigned)f2 == tag)
                    & ((unsigned)f3 == tag);
            } while (!okm && ++guard < (1 << 20));
            qxf = __int_as_float((int)(f1 >> 32));
            qyf = __int_as_float((int)(f2 >> 32));
            qzf = __int_as_float((int)(f3 >> 32));
        } else {
            // ---- wave0: poll all 64 quarters, lane i watches quarter i.
            //      Own quarter (lane == blk*4) from registers. ----
            ull* sp = rb + lane * SLOT_U64;
            const bool own = (lane == blk * QPB);
            ull l0 = own0, l1 = own1;
            bool ok = own;
            bool allok = __all(ok);

            // ---- phase 1: TDMA-aligned rounds (bounded: <=8 rounds,
            //      <=512 clock reads per epoch wait). SALU spin only ----
            ull tgt = ((__builtin_amdgcn_s_memrealtime() >> EPOCH_SHIFT) + 2)
                      << EPOCH_SHIFT;
            for (int r = 0; r < ALIGNED_MAX && !allok; ++r) {
                int spin = 0;
                while (__builtin_amdgcn_s_memrealtime() < tgt
                       && ++spin < SPIN_CAP) { }
                ull t0, t1;
                load_slot16(sp, t0, t1);
                const bool hit = (!ok) & TAGOK(t0) & TAGOK(t1);
                l0 = hit ? t0 : l0;
                l1 = hit ? t1 : l1;
                ok |= hit;
                allok = __all(ok);
                tgt = ((__builtin_amdgcn_s_memrealtime() >> EPOCH_SHIFT) + 1)
                      << EPOCH_SHIFT;
            }
            // ---- phase 2: proven free-running serial poll (R23) ----
            int g1 = 0;
            while (!allok && g1 < 32) {
                ull t0, t1;
                load_slot16(sp, t0, t1);
                const bool hit = (!ok) & TAGOK(t0) & TAGOK(t1);
                l0 = hit ? t0 : l0;
                l1 = hit ? t1 : l1;
                ok |= hit;
                allok = __all(ok);
                ++g1;
            }
            // ---- phase 3: escalation agent atomic-pair spin ----
            int g2 = 0;
            while (!ok) {
                l0 = __hip_atomic_load(sp + 0, __ATOMIC_RELAXED,
                                       __HIP_MEMORY_SCOPE_AGENT);
                l1 = __hip_atomic_load(sp + 1, __ATOMIC_RELAXED,
                                       __HIP_MEMORY_SCOPE_AGENT);
                ok = TAGOK(l0) & TAGOK(l1);
                if (++g2 > (1 << 20)) break;   // fail loud, never hang
            }

            double cd = __longlong_as_double(
                (long long)(((l0 >> 32) << 32) | (l1 >> 32)));
            int    ci = (int)(l0 & 0xFFFFull);

            // ---- speculative prefetch of THIS lane's candidate coords:
            //      issued before the butterfly so the L2 hit overlaps it ----
            const int    si = ci;
            const float* pc = P + (size_t)(unsigned)si * 3;
            const float px = pc[0];
            const float py = pc[1];
            const float pz = pc[2];

            // ---- 64-quarter argmax butterfly (DPP/permlane transport) ----
            argmax64(cd, ci, hi_half);

            // ---- out write: independent of the coord chain ----
            if (lane == 0 && blk == 0) out[g * NPOINTS + it + 1] = ci;

            // ---- winning lane -> broadcast its prefetched coords.
            //      Candidate indices unique across all 64 quarters. ----
            const ull mb = __ballot(si == ci);
            const int wl = (__ffsll(mb) - 1) & 63;
            qxf = __int_as_float(
                __builtin_amdgcn_readlane(__float_as_int(px), wl));
            qyf = __int_as_float(
                __builtin_amdgcn_readlane(__float_as_int(py), wl));
            qzf = __int_as_float(
                __builtin_amdgcn_readlane(__float_as_int(pz), wl));

            // ---- LDS mailbox: 3 tagged coord words ----
            if (lane < 3) {
                const unsigned coord =
                    (lane == 0) ? (unsigned)__float_as_int(qxf)
                  : (lane == 1) ? (unsigned)__float_as_int(qyf)
                                : (unsigned)__float_as_int(qzf);
                __hip_atomic_store(&s_mail[par][lane],
                                   ((ull)coord << 32) | (ull)tag,
                                   __ATOMIC_RELAXED,
                                   __HIP_MEMORY_SCOPE_WORKGROUP);
            }
        }

        // ---- winner coords from registers/LDS; no dependent P[wi] fetch ----
        qx = (double)qxf; qy = (double)qyf; qz = (double)qzf;
    }
}

extern "C" void kernel_launch(void* const* d_in, const int* in_sizes, int n_in,
                              void* d_out, int out_size, void* d_ws, size_t ws_size,
                              hipStream_t stream) {
    (void)in_sizes; (void)n_in; (void)out_size; (void)ws_size;
    // d_in[0] = npoints (scalar, fixed 2048 per setup), d_in[1] = t_in
    const float* t_in = (const float*)d_in[1];
    int* out = (int*)d_out;
    ull* slots = (ull*)d_ws;  // 32 KB used

    dim3 grid(NBATCH * KBLK);
    dim3 block(THREADS);
    void* args[] = { (void*)&t_in, (void*)&out, (void*)&slots };
    hipLaunchCooperativeKernel((const void*)fps_kernel, grid, block, args, 0, stream);
}

// Round 14
// 4310.246 us; speedup vs baseline: 1.7790x; 1.0852x over previous
//
#include <hip/hip_runtime.h>
#include <stdint.h>

// Farthest point sampling: b=16, n=65536, npoints=2048. Full-f64 decision
// pipeline (R5: harness ref is float64 ground-truth recompute).
//
// R30 = R23 (4.26 ms, best proven) + REGISTER-PINNED coordinates.
// The 10-rounds-overdue observation: VGPR_Count=84 is inconsistent with
// xd/yd/zd/dist[16] f64 state (>=128 VGPR). Since P is __restrict const,
// the compiler REMATERIALIZES coords by re-loading from P inside the
// update loop every iteration (~48 hidden L1/L2 loads/thread/iter,
// invisible in FETCH because P is L2-resident). That is the persistent
// ~2000cy/iter my chain models kept missing, why VALUBusy is only 30%,
// and why five sync-side probes (R21/22/23/27/29 TDMA) were all neutral:
// the UPDATE, not the wait, dominates. Fix: one opaque asm "+v" pin per
// coord value after init -- compiler can't re-derive them from P, must
// keep them resident. launch_bounds(256,1) gives a 512-VGPR budget and we
// run 1 block/CU by design, so ~170 VGPR costs nothing. Zero per-iter
// cost; arithmetic bit-identical.
// Tripwires: VGPR_Count must jump 84 -> ~170+ (pin engaged); WRITE_SIZE
// exactly 65632 KB (protocol untouched); absmax 0.
//
// Protocol (R23, proven): 16 blocks x 256 thr per batch; DPP/permlane
// argmax butterflies; per-wave publish of 16B quarters via atomic_swap_x2
// (single writer per word); wave0 polls 64 quarters (lane i watches
// quarter i, own-quarter register substitution), s_sleep(12) then 32
// rounds of one global_load_dwordx4 sc1, escalating to the agent
// atomic-pair spin; speculative P[] coord prefetch + ballot(si==ci) +
// readlane broadcast; waves1-3 spin on 3 self-tagged LDS coord words;
// parity double-buffer; unique 16-bit tags (poison 0 unmatchable);
// skew<=1; all spins guarded -- fail slow, never hang, never wrong.

#define NBATCH   16
#define NPTS     65536
#define NPOINTS  2048
#define KBLK     16                  // blocks per batch
#define THREADS  256
#define PPB      4096                // points per block
#define PPT      16                  // points per thread
#define QPB      4                   // quarters (waves) per block
#define SLOT_U64 2                   // 16 B per wave-quarter
#define REGION_U64 (KBLK * QPB * SLOT_U64) // 128 u64 = 1 KB per (parity,batch)

#define TAGOK(w) (((unsigned)((w) >> 16) & 0xFFFFu) == tag)

typedef unsigned int uint4v __attribute__((ext_vector_type(4)));
typedef unsigned int uint2v __attribute__((ext_vector_type(2)));
typedef unsigned long long ull;

// One 16-B device-scope load covering both quarter words.
__device__ __forceinline__ void load_slot16(const ull* p, ull& w0, ull& w1) {
    uint4v r;
    asm volatile("global_load_dwordx4 %0, %1, off sc1\n\t"
                 "s_waitcnt vmcnt(0)"
                 : "=v"(r) : "v"(p) : "memory");
    w0 = ((ull)r.y << 32) | r.x;
    w1 = ((ull)r.w << 32) | r.z;
}

// ---- argmax butterfly stages: (d,i) <- winner of self and partner ----
__device__ __forceinline__ void red_combine(double& d, int& i,
                                            double od, int oi) {
    const bool t = (od > d) || (od == d && oi < i);
    d = t ? od : d; i = t ? oi : i;
}

template <int CTRL>
__device__ __forceinline__ void red_dpp(double& d, int& i) {
    const int hi = __double2hiint(d), lo = __double2loint(d);
    const int ohi = __builtin_amdgcn_update_dpp(hi, hi, CTRL, 0xF, 0xF, false);
    const int olo = __builtin_amdgcn_update_dpp(lo, lo, CTRL, 0xF, 0xF, false);
    const int oi  = __builtin_amdgcn_update_dpp(i,  i,  CTRL, 0xF, 0xF, false);
    red_combine(d, i, __hiloint2double(ohi, olo), oi);
}

__device__ __forceinline__ void red_swz16(double& d, int& i) {
    // ds_swizzle BitMode xor16: offset = (16<<10) | 0x1F = 0x401F
    const int ohi = __builtin_amdgcn_ds_swizzle(__double2hiint(d), 0x401F);
    const int olo = __builtin_amdgcn_ds_swizzle(__double2loint(d), 0x401F);
    const int oi  = __builtin_amdgcn_ds_swizzle(i, 0x401F);
    red_combine(d, i, __hiloint2double(ohi, olo), oi);
}

__device__ __forceinline__ void red_x32(double& d, int& i, bool hi_half) {
    // permlane32_swap(v,v): partner = hi_half ? r[0] : r[1].
    const unsigned hi = (unsigned)__double2hiint(d);
    const unsigned lo = (unsigned)__double2loint(d);
    uint2v rh = __builtin_amdgcn_permlane32_swap(hi, hi, false, false);
    uint2v rl = __builtin_amdgcn_permlane32_swap(lo, lo, false, false);
    uint2v ri = __builtin_amdgcn_permlane32_swap((unsigned)i, (unsigned)i,
                                                 false, false);
    const int ohi = (int)(hi_half ? rh[0] : rh[1]);
    const int olo = (int)(hi_half ? rl[0] : rl[1]);
    const int oi  = (int)(hi_half ? ri[0] : ri[1]);
    red_combine(d, i, __hiloint2double(ohi, olo), oi);
}

// Full 64-lane argmax (all lanes end with the global winner).
__device__ __forceinline__ void argmax64(double& d, int& i, bool hi_half) {
    red_dpp<0xB1>(d, i);    // xor1  (quad_perm 1,0,3,2)
    red_dpp<0x4E>(d, i);    // xor2  (quad_perm 2,3,0,1)
    red_dpp<0x141>(d, i);   // i^7 row_half_mirror -> 8-max
    red_dpp<0x140>(d, i);   // i^15 row_mirror     -> 16-max
    red_swz16(d, i);        // xor16               -> 32-max
    red_x32(d, i, hi_half); // xor32               -> 64-max
}

__global__ __launch_bounds__(THREADS, 1)
void fps_kernel(const float* __restrict__ pts, int* __restrict__ out,
                ull* __restrict__ slots)
{
    const int bid  = blockIdx.x;
    const int g    = bid & 15;       // batch (XCD co-location swizzle)
    const int blk  = bid >> 4;       // block within batch, 0..15
    const int tid  = threadIdx.x;
    const int lane = tid & 63;
    const int wave = tid >> 6;       // 0..3
    const bool hi_half = (lane >= 32);

    const float* __restrict__ P = pts + (size_t)g * (NPTS * 3);

    // mailbox: [par][k] = coord_k|tag for k=0,1,2 (x,y,z); [3] unused pad
    __shared__ ull s_mail[2][4];

    // Pre-widened f64 coords + f64 dist.
    double xd[PPT], yd[PPT], zd[PPT], dist[PPT];
    const int base = blk * PPB;
#pragma unroll
    for (int j = 0; j < PPT; ++j) {
        const int idx = base + j * THREADS + tid;
        xd[j] = (double)P[idx * 3 + 0];
        yd[j] = (double)P[idx * 3 + 1];
        zd[j] = (double)P[idx * 3 + 2];
        dist[j] = 1e10;              // never survives iteration 0
    }
    // ---- REGISTER PIN: opaque pass defeats rematerialization-by-reload.
    //      Without this the compiler re-loads all 48 coords from P every
    //      iteration (VGPR_Count 84 proved it). One-time, zero per-iter
    //      cost, bit-identical values. ----
#pragma unroll
    for (int j = 0; j < PPT; ++j) {
        asm volatile("" : "+v"(xd[j]), "+v"(yd[j]), "+v"(zd[j]));
    }
    if (tid < 8) ((ull*)s_mail)[tid] = 0ull;  // tags never 0
    __syncthreads();                 // once, before the loop

    double qx = (double)P[0], qy = (double)P[1], qz = (double)P[2];
    if (blk == 0 && tid == 0) out[g * NPOINTS] = 0;

    for (int it = 0; it < NPOINTS - 1; ++it) {
        // ---- f64 min-dist update + thread-local argmax (first-max) ----
        double bd = -1.0;
        int    bi = 0x7FFFFFFF;
        {
#pragma clang fp contract(off)
#pragma unroll
            for (int j = 0; j < PPT; ++j) {
                const double dx = xd[j] - qx;
                const double dy = yd[j] - qy;
                const double dz = zd[j] - qz;
                const double d  = (dx * dx + dy * dy) + dz * dz;
                const double nd = fmin(dist[j], d);
                dist[j] = nd;
                const bool t = nd > bd;          // strict: first-max kept
                bd = t ? nd : bd;
                bi = t ? (base + j * THREADS + tid) : bi;
            }
        }

        // ---- 64-lane argmax butterfly (DPP/permlane transport) ----
        argmax64(bd, bi, hi_half);

        const unsigned tag = (unsigned)(it + 1);
        const int par = it & 1;
        ull* rb = slots + (size_t)(par * NBATCH + g) * REGION_U64;

        // ---- this wave's quarter words (publish + own substitution) ----
        const ull B  = (ull)__double_as_longlong(bd);
        const ull TI = ((ull)tag << 16) | (ull)((unsigned)bi & 0xFFFFu);
        const ull own0 = ((B >> 32) << 32) | TI;
        const ull own1 = ((B & 0xFFFFFFFFull) << 32) | TI;

        // ---- per-wave publish via no-return atomic swap (single writer
        //      per word -> swap == store) ----
        if (lane < 2) {
            ull* dst = rb + (blk * QPB + wave) * SLOT_U64 + lane;
            const ull v = (lane == 0) ? own0 : own1;
            asm volatile("global_atomic_swap_x2 %0, %1, off"
                         :: "v"(dst), "v"(v) : "memory");
        }

        float qxf, qyf, qzf;         // this iteration's winner coords (f32)

        if (wave != 0) {
            // ---- winner coords from LDS (3 self-tagged words). This IS
            //      the rendezvous; parity leftovers carry tag it-1 ----
            ull f1, f2, f3;
            int guard = 0;
            bool okm;
            do {
                f1 = __hip_atomic_load(&s_mail[par][0], __ATOMIC_RELAXED,
                                       __HIP_MEMORY_SCOPE_WORKGROUP);
                f2 = __hip_atomic_load(&s_mail[par][1], __ATOMIC_RELAXED,
                                       __HIP_MEMORY_SCOPE_WORKGROUP);
                f3 = __hip_atomic_load(&s_mail[par][2], __ATOMIC_RELAXED,
                                       __HIP_MEMORY_SCOPE_WORKGROUP);
                okm = ((unsigned)f1 == tag) & ((unsigned)f2 == tag)
                    & ((unsigned)f3 == tag);
            } while (!okm && ++guard < (1 << 20));
            qxf = __int_as_float((int)(f1 >> 32));
            qyf = __int_as_float((int)(f2 >> 32));
            qzf = __int_as_float((int)(f3 >> 32));
        } else {
            // ---- wave0: poll all 64 quarters, lane i watches quarter i
            //      (16-B stride, contiguous 1 KB = 16 lines).
            //      Own quarter (lane == blk*4) from registers. ----
            ull* sp = rb + lane * SLOT_U64;
            const bool own = (lane == blk * QPB);
            ull l0 = own0, l1 = own1;
            bool ok = own;
            __builtin_amdgcn_s_sleep(12);  // ~768 cy: skip guaranteed-miss rounds
            int g1 = 0;
            while (!ok && g1 < 32) {
                ull t0, t1;
                load_slot16(sp, t0, t1);
                const bool hit = (!ok) & TAGOK(t0) & TAGOK(t1);
                l0 = hit ? t0 : l0;
                l1 = hit ? t1 : l1;
                ok |= hit;
                ++g1;
            }
            int g2 = 0;
            while (!ok) {
                // escalation: proven agent atomic-pair spin
                l0 = __hip_atomic_load(sp + 0, __ATOMIC_RELAXED,
                                       __HIP_MEMORY_SCOPE_AGENT);
                l1 = __hip_atomic_load(sp + 1, __ATOMIC_RELAXED,
                                       __HIP_MEMORY_SCOPE_AGENT);
                ok = TAGOK(l0) & TAGOK(l1);
                if (++g2 > (1 << 20)) break;   // fail loud, never hang
            }

            double cd = __longlong_as_double(
                (long long)(((l0 >> 32) << 32) | (l1 >> 32)));
            int    ci = (int)(l0 & 0xFFFFull);

            // ---- speculative prefetch of THIS lane's candidate coords:
            //      issued before the butterfly so the L2 hit overlaps it ----
            const int    si = ci;
            const float* pc = P + (size_t)(unsigned)si * 3;
            const float px = pc[0];
            const float py = pc[1];
            const float pz = pc[2];

            // ---- 64-quarter argmax butterfly (DPP/permlane transport) ----
            argmax64(cd, ci, hi_half);

            // ---- out write: independent of the coord chain ----
            if (lane == 0 && blk == 0) out[g * NPOINTS + it + 1] = ci;

            // ---- winning lane -> broadcast its prefetched coords.
            //      Candidate indices unique across all 64 quarters. ----
            const ull mb = __ballot(si == ci);
            const int wl = (__ffsll(mb) - 1) & 63;
            qxf = __int_as_float(
                __builtin_amdgcn_readlane(__float_as_int(px), wl));
            qyf = __int_as_float(
                __builtin_amdgcn_readlane(__float_as_int(py), wl));
            qzf = __int_as_float(
                __builtin_amdgcn_readlane(__float_as_int(pz), wl));

            // ---- LDS mailbox: 3 tagged coord words ----
            if (lane < 3) {
                const unsigned coord =
                    (lane == 0) ? (unsigned)__float_as_int(qxf)
                  : (lane == 1) ? (unsigned)__float_as_int(qyf)
                                : (unsigned)__float_as_int(qzf);
                __hip_atomic_store(&s_mail[par][lane],
                                   ((ull)coord << 32) | (ull)tag,
                                   __ATOMIC_RELAXED,
                                   __HIP_MEMORY_SCOPE_WORKGROUP);
            }
        }

        // ---- winner coords from registers/LDS; no dependent P[wi] fetch ----
        qx = (double)qxf; qy = (double)qyf; qz = (double)qzf;
    }
}

extern "C" void kernel_launch(void* const* d_in, const int* in_sizes, int n_in,
                              void* d_out, int out_size, void* d_ws, size_t ws_size,
                              hipStream_t stream) {
    (void)in_sizes; (void)n_in; (void)out_size; (void)ws_size;
    // d_in[0] = npoints (scalar, fixed 2048 per setup), d_in[1] = t_in
    const float* t_in = (const float*)d_in[1];
    int* out = (int*)d_out;
    ull* slots = (ull*)d_ws;  // 32 KB used

    dim3 grid(NBATCH * KBLK);
    dim3 block(THREADS);
    void* args[] = { (void*)&t_in, (void*)&out, (void*)&slots };
    hipLaunchCooperativeKernel((const void*)fps_kernel, grid, block, args, 0, stream);
}